// Round 1
// baseline (62.318 us; speedup 1.0000x reference)
//
#include <hip/hip_runtime.h>

// SConv2d with MAJ-gate tree (MAJ_DIM=3), N=8, C_IN=3, C_OUT=64, H=W=64, 3x3 conv s1 p1.
// maj3(a,b,c) = (a+b+c - abc)/2  (closed form of the combinatorial reference).
// Level 1 (over kernel-width j):  m1 = dot4( (w0,w1,w2,w0w1w2)*0.5 , (x0,x1,x2,x0x1x2) )
// Level 2 (over kernel-height i), Level 3 (over channels c): plain maj3.

#define NC_OUT 64

__global__ __launch_bounds__(256) void sconv_maj_kernel(
    const float* __restrict__ x,      // [8,3,64,64]
    const float* __restrict__ wgt,    // [64,3,3,3] -> flat [64,27]
    float* __restrict__ out)          // [8,64,64,64]
{
    __shared__ float  xt[3 * 3 * 66 + 2];   // x tile: [c][i][col], col in [0,66)
    __shared__ float4 wl[NC_OUT * 9];       // per (co, group g=c*3+i): (w0,w1,w2,w0w1w2)*0.5

    const int bid = blockIdx.x;
    const int n   = bid >> 6;     // image index
    const int h   = bid & 63;     // output row
    const int tid = threadIdx.x;

    // ---- stage pre-scaled weights: 64*9 = 576 groups ----
    for (int e = tid; e < NC_OUT * 9; e += 256) {
        const int co = e / 9;
        const int g  = e - co * 9;
        const float w0 = wgt[co * 27 + g * 3 + 0];
        const float w1 = wgt[co * 27 + g * 3 + 1];
        const float w2 = wgt[co * 27 + g * 3 + 2];
        wl[e] = make_float4(0.5f * w0, 0.5f * w1, 0.5f * w2, 0.5f * w0 * w1 * w2);
    }

    // ---- stage x tile: rows h-1..h+1, cols -1..64, 3 channels (zero pad) ----
    for (int e = tid; e < 3 * 3 * 66; e += 256) {
        const int c   = e / 198;
        const int rem = e - c * 198;
        const int r   = rem / 66;
        const int col = rem - r * 66;
        const int gh  = h - 1 + r;
        const int gw  = col - 1;
        float v = 0.0f;
        if ((unsigned)gh < 64u && (unsigned)gw < 64u)
            v = x[((n * 3 + c) * 64 + gh) * 64 + gw];
        xt[e] = v;
    }
    __syncthreads();

    const int w  = tid & 63;   // output col (lane -> coalesced stores)
    const int cq = tid >> 6;   // channel quarter: 16 channels per thread

    // ---- per-position patch values + width-products (channel-loop invariant) ----
    float xv0[9], xv1[9], xv2[9], xp[9];
    #pragma unroll
    for (int c = 0; c < 3; ++c) {
        #pragma unroll
        for (int i = 0; i < 3; ++i) {
            const int g = c * 3 + i;
            const float a = xt[g * 66 + w + 0];
            const float b = xt[g * 66 + w + 1];
            const float d = xt[g * 66 + w + 2];
            xv0[g] = a; xv1[g] = b; xv2[g] = d;
            xp[g] = a * b * d;
        }
    }

    // ---- channel loop: 16 output channels per thread ----
    #pragma unroll
    for (int t = 0; t < 16; ++t) {
        const int co = cq * 16 + t;
        float m1[9];
        #pragma unroll
        for (int g = 0; g < 9; ++g) {
            const float4 wv = wl[co * 9 + g];   // lane-uniform -> LDS broadcast
            // m1 = 0.5*(w0*x0 + w1*x1 + w2*x2 - w0w1w2 * x0x1x2), 0.5 folded into wv
            m1[g] = fmaf(wv.x, xv0[g],
                    fmaf(wv.y, xv1[g],
                    fmaf(wv.z, xv2[g], -wv.w * xp[g])));
        }
        float m2[3];
        #pragma unroll
        for (int c = 0; c < 3; ++c) {
            const float a = m1[c * 3 + 0];
            const float b = m1[c * 3 + 1];
            const float d = m1[c * 3 + 2];
            m2[c] = 0.5f * ((a + b + d) - a * b * d);
        }
        const float a = m2[0], b = m2[1], d = m2[2];
        const float o = 0.5f * ((a + b + d) - a * b * d);
        out[((n * NC_OUT + co) * 64 + h) * 64 + w] = o;
    }
}

extern "C" void kernel_launch(void* const* d_in, const int* in_sizes, int n_in,
                              void* d_out, int out_size, void* d_ws, size_t ws_size,
                              hipStream_t stream) {
    const float* x   = (const float*)d_in[0];   // 8*3*64*64
    const float* wgt = (const float*)d_in[1];   // 64*3*3*3
    float* out = (float*)d_out;                 // 8*64*64*64
    // grid: one block per (n, h) row: 8*64 = 512 blocks
    sconv_maj_kernel<<<dim3(512), dim3(256), 0, stream>>>(x, wgt, out);
}

// Round 2
// 61.785 us; speedup vs baseline: 1.0086x; 1.0086x over previous
//
#include <hip/hip_runtime.h>

// SConv2d with MAJ-gate tree (MAJ_DIM=3), N=8, C_IN=3, C_OUT=64, H=W=64, 3x3 conv s1 p1.
// maj3(a,b,c) = (a+b+c - abc)/2  (closed form of the combinatorial reference; verified R1).
// Level 1 (over kernel-width j):  m1 = dot4( (w0,w1,w2,w0w1w2)*0.5 , (x0,x1,x2,x0x1x2) )
// Level 2 (over kernel-height i), Level 3 (over channels c): plain maj3.
//
// R2: grid 512 -> 2048 blocks (channel-quartered) for occupancy; 4 channels/thread.

#define NC_OUT 64

__global__ __launch_bounds__(256, 4) void sconv_maj_kernel(
    const float* __restrict__ x,      // [8,3,64,64]
    const float* __restrict__ wgt,    // [64,3,3,3] -> flat [64,27]
    float* __restrict__ out)          // [8,64,64,64]
{
    __shared__ float  xt[3 * 3 * 66];   // x tile: [c][i][col], col in [0,66)
    __shared__ float4 wl[16 * 9];       // this block's 16 channels: (w0,w1,w2,w0w1w2)*0.5

    const int bid = blockIdx.x;
    const int q   = bid & 3;            // channel quarter: channels q*16 .. q*16+15
    const int h   = (bid >> 2) & 63;    // output row
    const int n   = bid >> 8;           // image index
    const int tid = threadIdx.x;

    // ---- stage pre-scaled weights: 16 channels * 9 groups = 144 entries ----
    if (tid < 144) {
        const int t  = tid / 9;         // local channel 0..15
        const int g  = tid - t * 9;     // group = c*3+i
        const int co = q * 16 + t;
        const float w0 = wgt[co * 27 + g * 3 + 0];
        const float w1 = wgt[co * 27 + g * 3 + 1];
        const float w2 = wgt[co * 27 + g * 3 + 2];
        wl[tid] = make_float4(0.5f * w0, 0.5f * w1, 0.5f * w2, 0.5f * w0 * w1 * w2);
    }

    // ---- stage x tile: rows h-1..h+1, cols -1..64, 3 channels (zero pad) ----
    for (int e = tid; e < 3 * 3 * 66; e += 256) {
        const int c   = e / 198;
        const int rem = e - c * 198;
        const int r   = rem / 66;
        const int col = rem - r * 66;
        const int gh  = h - 1 + r;
        const int gw  = col - 1;
        float v = 0.0f;
        if ((unsigned)gh < 64u && (unsigned)gw < 64u)
            v = x[((n * 3 + c) * 64 + gh) * 64 + gw];
        xt[e] = v;
    }
    __syncthreads();

    const int w = tid & 63;   // output col (lane -> coalesced stores)
    const int s = tid >> 6;   // subgroup: local channels s*4 .. s*4+3 (wave-uniform)

    // ---- per-position patch values + width-products (channel-loop invariant) ----
    float xa[9], xb[9], xd[9], xp[9];
    #pragma unroll
    for (int g = 0; g < 9; ++g) {
        const float a = xt[g * 66 + w + 0];
        const float b = xt[g * 66 + w + 1];
        const float d = xt[g * 66 + w + 2];
        xa[g] = a; xb[g] = b; xd[g] = d;
        xp[g] = a * b * d;
    }

    // ---- 4 output channels per thread ----
    #pragma unroll
    for (int t = 0; t < 4; ++t) {
        const int lc = s * 4 + t;           // local channel (wave-uniform -> LDS broadcast)
        const int co = q * 16 + lc;
        float m1[9];
        #pragma unroll
        for (int g = 0; g < 9; ++g) {
            const float4 wv = wl[lc * 9 + g];
            // m1 = 0.5*(w0*x0 + w1*x1 + w2*x2 - w0w1w2 * x0x1x2), 0.5 folded into wv
            m1[g] = fmaf(wv.x, xa[g],
                    fmaf(wv.y, xb[g],
                    fmaf(wv.z, xd[g], -wv.w * xp[g])));
        }
        float m2[3];
        #pragma unroll
        for (int c = 0; c < 3; ++c) {
            const float a = m1[c * 3 + 0];
            const float b = m1[c * 3 + 1];
            const float d = m1[c * 3 + 2];
            m2[c] = 0.5f * ((a + b + d) - a * b * d);
        }
        const float a = m2[0], b = m2[1], d = m2[2];
        const float o = 0.5f * ((a + b + d) - a * b * d);
        out[((n * NC_OUT + co) * 64 + h) * 64 + w] = o;
    }
}

extern "C" void kernel_launch(void* const* d_in, const int* in_sizes, int n_in,
                              void* d_out, int out_size, void* d_ws, size_t ws_size,
                              hipStream_t stream) {
    const float* x   = (const float*)d_in[0];   // 8*3*64*64
    const float* wgt = (const float*)d_in[1];   // 64*3*3*3
    float* out = (float*)d_out;                 // 8*64*64*64
    // grid: (n, h, quarter): 8*64*4 = 2048 blocks
    sconv_maj_kernel<<<dim3(2048), dim3(256), 0, stream>>>(x, wgt, out);
}